// Round 6
// baseline (259.275 us; speedup 1.0000x reference)
//
#include <hip/hip_runtime.h>

// ---------------------------------------------------------------------------
// TemporalHyperedge: loss[b] = 0.2 * sum_n ||cur[b]@r_proj - W@pre[b]||_2
//                              + sum_n (max_m W[n,m] + 0.001*||W[n,:]||_2)
// W = incidence_m masked to > 0.01. Output = [loss(32) , incidence_m(2048^2)].
//
// R10 change: split the per-CU sync domain. R9 proved the gemm is not
// byte-bound (FETCH 152->66 MB, dur unchanged 98us); all prior variants share
// ONE barrier domain per CU (16 waves in lockstep), so per-tile vmcnt+barrier
// drains are fully exposed. Now: 512 blocks x 8 waves (128n x 256d tile),
// 3-deep LDS rotation (72.6 KB) -> exactly 2 blocks/CU, same 16 waves/CU,
// same per-CU MFMA + LDS-read totals, but two INDEPENDENT barrier domains
// that overlap each other's stalls (m114 co-scheduling). Everything else
// (swizzle, counted vmcnt depth-2, epilogue fusion, prep) unchanged from R9.
// ---------------------------------------------------------------------------

typedef __attribute__((ext_vector_type(8))) short bf16x8;
typedef __attribute__((ext_vector_type(8))) unsigned short ushort8;
typedef __attribute__((ext_vector_type(16))) float f32x16;

__device__ __forceinline__ unsigned short f2bf(float f) {
    union { float f; unsigned u; } x; x.f = f;
    unsigned r = x.u + 0x7fffu + ((x.u >> 16) & 1u);   // RNE
    return (unsigned short)(r >> 16);
}

#define GLL16(g, l)                                                         \
    __builtin_amdgcn_global_load_lds(                                       \
        (const __attribute__((address_space(1))) void*)(g),                 \
        (__attribute__((address_space(3))) void*)(l), 16, 0, 0)

// --------------------------------------------------------------------------
// transpose_64x64: src f32 (R,C) tile (r0,c0) -> dst bf16 (C,R).
// --------------------------------------------------------------------------
__device__ __forceinline__ void transpose_64x64(
    const float* __restrict__ src, unsigned short* __restrict__ dst,
    int R, int C, int r0, int c0, unsigned short* __restrict__ tile) {
    const int t = threadIdx.x;
    const int fr = t >> 4, fc = (t & 15) * 4;
#pragma unroll
    for (int it = 0; it < 4; ++it) {
        int m = fr + it * 16;
        float4 v = *(const float4*)(src + (size_t)(r0 + m) * C + c0 + fc);
        tile[(fc + 0) * 68 + m] = f2bf(v.x);
        tile[(fc + 1) * 68 + m] = f2bf(v.y);
        tile[(fc + 2) * 68 + m] = f2bf(v.z);
        tile[(fc + 3) * 68 + m] = f2bf(v.w);
    }
    __syncthreads();
    const int d = t >> 2, m0 = (t & 3) * 16;
    unsigned short v[16];
#pragma unroll
    for (int j = 0; j < 4; ++j)
        *(ushort4*)(v + j * 4) = *(const ushort4*)(tile + d * 68 + m0 + j * 4);
    unsigned short* dp = dst + (size_t)(c0 + d) * R + r0 + m0;
    ushort8 p0, p1;
#pragma unroll
    for (int j = 0; j < 8; ++j) { p0[j] = v[j]; p1[j] = v[8 + j]; }
    *(ushort8*)(dp) = p0;
    *(ushort8*)(dp + 8) = p1;
}

// --------------------------------------------------------------------------
// prep_all — block sections:
//   [0,2048)     : incidence row: copy-out, -masked bf16 W, crow=l1+1e-3*l2
//                  (block 0 also zeroes out_loss[0..31])
//   [2048,6144)  : pre (32,2048,256) -> preT (32,256,2048) bf16 transpose
//   [6144,6160)  : r_proj (256,256) -> rprojT bf16 transpose
//   [6160,8208)  : cur f32 -> curbf bf16 (same layout)
// --------------------------------------------------------------------------
__global__ __launch_bounds__(256) void prep_all(
    const float* __restrict__ inc, float* __restrict__ out_inc,
    unsigned short* __restrict__ Wneg, float* __restrict__ crow,
    const float* __restrict__ pre, unsigned short* __restrict__ preT,
    const float* __restrict__ r_proj, unsigned short* __restrict__ rprojT,
    const float* __restrict__ cur, unsigned short* __restrict__ curbf,
    float* __restrict__ out_loss) {
    __shared__ unsigned short tile[64 * 68];
    __shared__ float smax[4], ssum[4];
    const int bid = blockIdx.x;
    const int t = threadIdx.x;

    if (bid < 2048) {
        if (bid == 0 && t < 32) out_loss[t] = 0.f;
        const int row = bid;
        const float4* src = (const float4*)(inc + (size_t)row * 2048);
        float4* dst = (float4*)(out_inc + (size_t)row * 2048);
        ushort4* wp = (ushort4*)(Wneg + (size_t)row * 2048);
        float lmax = 0.f, ss = 0.f;
#pragma unroll
        for (int it = 0; it < 2; ++it) {
            int i = it * 256 + t;
            float4 v = src[i];
            dst[i] = v;
            float w0 = v.x > 0.01f ? v.x : 0.f;
            float w1 = v.y > 0.01f ? v.y : 0.f;
            float w2 = v.z > 0.01f ? v.z : 0.f;
            float w3 = v.w > 0.01f ? v.w : 0.f;
            ushort4 p;
            p.x = f2bf(-w0); p.y = f2bf(-w1); p.z = f2bf(-w2); p.w = f2bf(-w3);
            wp[i] = p;
            lmax = fmaxf(lmax, fmaxf(fmaxf(w0, w1), fmaxf(w2, w3)));
            ss += w0 * w0 + w1 * w1 + w2 * w2 + w3 * w3;
        }
#pragma unroll
        for (int off = 32; off; off >>= 1) {
            lmax = fmaxf(lmax, __shfl_down(lmax, off));
            ss += __shfl_down(ss, off);
        }
        int wv = t >> 6, ln = t & 63;
        if (ln == 0) { smax[wv] = lmax; ssum[wv] = ss; }
        __syncthreads();
        if (t == 0) {
            float m = fmaxf(fmaxf(smax[0], smax[1]), fmaxf(smax[2], smax[3]));
            float s = ssum[0] + ssum[1] + ssum[2] + ssum[3];
            crow[row] = m + 0.001f * sqrtf(s);
        }
    } else if (bid < 6144) {
        const int tt = bid - 2048;
        const int b = tt >> 7;
        const int mt = (tt & 127) >> 2;
        const int dt = tt & 3;
        transpose_64x64(pre + (size_t)b * 524288, preT + (size_t)b * 524288,
                        2048, 256, mt * 64, dt * 64, tile);
    } else if (bid < 6160) {
        const int tt = bid - 6144;
        transpose_64x64(r_proj, rprojT, 256, 256, (tt >> 2) * 64, (tt & 3) * 64,
                        tile);
    } else {
        // cur -> bf16: 2048 blocks x 256 thr x 32 f32
        const size_t base = (size_t)(bid - 6160) * 8192;
#pragma unroll
        for (int i = 0; i < 8; ++i) {
            size_t idx = base + (size_t)(i * 256 + t) * 4;
            float4 v = *(const float4*)(cur + idx);
            ushort4 p;
            p.x = f2bf(v.x); p.y = f2bf(v.y); p.z = f2bf(v.z); p.w = f2bf(v.w);
            *(ushort4*)(curbf + idx) = p;
        }
    }
}

// --------------------------------------------------------------------------
// gemm_diff: block = 128n x 256d, BK=32, 72 K-tiles (64 Wneg/preT + 8
// curbf/rprojT). 32x32x16 MFMA, 8 waves (2m x 4n), wave tile 64x64
// (acc f32x16[2][2]). 512 blocks -> 2 blocks/CU (LDS-forced), two
// independent barrier domains per CU.
//
// Grid remap: xcd = i&7, slot = i>>3 (0..63), panel = slot&15,
// batch = xcd + 8*(slot>>4). Per XCD: 16 panels x 4 batches, 64 blocks
// co-resident -> preT/Wneg L2-shared within the XCD (R9-proven).
//
// LDS: 3-deep rotation, per tile A(8KB)+B(16KB) -> 72.6 KB total.
// Swizzle (64B rows, 4 x 16B chunks): LDS[r][p] = G[r][p ^ ((r>>1)&3)],
// staged via source-side chunk permute, read-side XOR q2.
//
// Pipeline: 2 tiles (6 loads/wave) in flight. Per tile t:
//   s_waitcnt vmcnt(3)   [tile t landed; t+1 in flight]  (vmcnt(0) at t=71)
//   s_barrier            [all waves' DMA visible; WAR on buf[(t+2)%3] closed]
//   stage(t+2)           [3 GLL16/wave into buf[(t+2)%3]]
//   ks-loop on buf[t%3]  [2 ks x (2 A + 2 B b128 reads + 4 MFMA) per wave]
//
// Epilogue: recon = sqrt(ssq); block-reduce 0.2*sum(recon) + sum(crow[panel])
// -> one atomicAdd into out_loss[b] (16 adds per batch).
// --------------------------------------------------------------------------
__global__ __launch_bounds__(512) void gemm_diff(
    const unsigned short* __restrict__ Wneg,    // (2048,2048) bf16 neg+masked
    const unsigned short* __restrict__ curbf,   // (32,2048,256) bf16
    const unsigned short* __restrict__ preT,    // (32,256,2048) bf16
    const unsigned short* __restrict__ rprojT,  // (256,256) bf16
    const float* __restrict__ crow,             // (2048)
    float* __restrict__ out_loss)               // (32)
{
    const int i    = blockIdx.x;                 // 0..511
    const int xcd  = i & 7;
    const int slot = i >> 3;                     // 0..63
    const int n0   = (slot & 15) * 128;          // panel
    const int b    = xcd + ((slot >> 4) << 3);   // batch

    __shared__ unsigned short Ab[3 * 128 * 32];  // 24 KB
    __shared__ unsigned short Bb[3 * 256 * 32];  // 48 KB
    __shared__ float ssq[128];
    __shared__ float red[8];

    const int tid  = threadIdx.x;
    const int w    = tid >> 6;                   // 0..7
    const int lane = tid & 63;
    const int l32  = lane & 31;
    const int half = lane >> 5;
    const int wm   = w >> 2;                     // 0..1 (n-band of 64)
    const int wn   = w & 3;                      // 0..3 (d-band of 64)
    const int w16  = w * 16;
    const int srow  = lane >> 2;                 // staging row within 16
    const int sbyte = ((lane & 3) ^ ((lane >> 3) & 3)) * 16;  // swizzled src
    const int q2    = (l32 >> 1) & 3;            // read-side swizzle

    if (tid < 128) ssq[tid] = 0.f;

    f32x16 acc[2][2] = {};

    const unsigned short* curA = curbf + (size_t)b * 2048 * 256 + (size_t)n0 * 256;
    const unsigned short* preB = preT + (size_t)b * 256 * 2048;
    const unsigned short* An   = Wneg + (size_t)n0 * 2048;

    // stage tile into buf BUF (A 128x32: 1 GLL16/wave; B 256x32: 2 GLL16/wave)
#define STAGE(BUF, aB, aS, bB, bS, KK)                                         \
    {                                                                          \
        GLL16((const char*)((aB) + (size_t)(w16 + srow) * (aS) + (KK)) + sbyte,\
              (char*)Ab + (BUF) * 8192 + w16 * 64);                            \
        GLL16((const char*)((bB) + (size_t)(w16 + srow) * (bS) + (KK)) + sbyte,\
              (char*)Bb + (BUF) * 16384 + w16 * 64);                           \
        GLL16((const char*)((bB) + (size_t)(128 + w16 + srow) * (bS) + (KK)) + sbyte,\
              (char*)Bb + (BUF) * 16384 + (128 + w16) * 64);                   \
    }

    // ---- prologue: tiles 0,1 in flight (6 loads/wave)
    STAGE(0, An, 2048, preB, 2048, 0);
    STAGE(1, An, 2048, preB, 2048, 32);

    int bc = 0;  // buffer of tile t
    for (int t = 0; t < 72; ++t) {
        if (t < 71) asm volatile("s_waitcnt vmcnt(3)" ::: "memory");
        else        asm volatile("s_waitcnt vmcnt(0)" ::: "memory");
        asm volatile("s_barrier" ::: "memory");

        if (t < 70) {
            const int t2 = t + 2;
            const int bs = bc >= 1 ? bc - 1 : bc + 2;   // (t+2) % 3
            if (t2 < 64) { STAGE(bs, An,   2048, preB,   2048, t2 * 32); }
            else         { STAGE(bs, curA, 256,  rprojT, 256,  (t2 - 64) * 32); }
        }

        const unsigned short* Ac = Ab + bc * 4096;   // elements
        const unsigned short* Bc = Bb + bc * 8192;   // elements
#pragma unroll
        for (int ks = 0; ks < 2; ++ks) {
            const int co = (((ks << 1) + half) ^ q2) << 3;
            bf16x8 af[2], bfr[2];
#pragma unroll
            for (int mi = 0; mi < 2; ++mi)
                af[mi] = *(const bf16x8*)(Ac + (wm * 64 + mi * 32 + l32) * 32 + co);
#pragma unroll
            for (int ni = 0; ni < 2; ++ni)
                bfr[ni] = *(const bf16x8*)(Bc + (wn * 64 + ni * 32 + l32) * 32 + co);
#pragma unroll
            for (int mi = 0; mi < 2; ++mi)
#pragma unroll
                for (int ni = 0; ni < 2; ++ni)
                    acc[mi][ni] = __builtin_amdgcn_mfma_f32_32x32x16_bf16(
                        af[mi], bfr[ni], acc[mi][ni], 0, 0, 0);
        }
        bc = bc < 2 ? bc + 1 : 0;
    }
    __syncthreads();

    // 32x32 C/D layout: col(d)=lane&31, row(n)=(reg&3)+8*(reg>>2)+4*half
#pragma unroll
    for (int mi = 0; mi < 2; ++mi)
#pragma unroll
        for (int reg = 0; reg < 16; ++reg) {
            float s = 0.f;
#pragma unroll
            for (int ni = 0; ni < 2; ++ni) {
                float v = acc[mi][ni][reg];
                s += v * v;
            }
            s += __shfl_xor(s, 1);
            s += __shfl_xor(s, 2);
            s += __shfl_xor(s, 4);
            s += __shfl_xor(s, 8);
            s += __shfl_xor(s, 16);
            if (l32 == 0) {
                const int row = wm * 64 + mi * 32 +
                                (reg & 3) + 8 * (reg >> 2) + 4 * half;
                atomicAdd(&ssq[row], s);  // 4-way (wn)
            }
        }
    __syncthreads();

    // epilogue reduce: 0.2*sum_n sqrt(ssq[n]) + sum_{n in panel} crow[n]
    float contrib = 0.f;
    if (tid < 128) contrib = 0.2f * sqrtf(ssq[tid]) + crow[n0 + tid];
#pragma unroll
    for (int off = 32; off; off >>= 1) contrib += __shfl_down(contrib, off);
    if (lane == 0) red[w] = contrib;
    __syncthreads();
    if (tid == 0) {
        float s = 0.f;
#pragma unroll
        for (int k = 0; k < 8; ++k) s += red[k];
        atomicAdd(out_loss + b, s);  // 16 adds per batch
    }
}

// --------------------------------------------------------------------------
extern "C" void kernel_launch(void* const* d_in, const int* in_sizes, int n_in,
                              void* d_out, int out_size, void* d_ws, size_t ws_size,
                              hipStream_t stream) {
    const float* cur    = (const float*)d_in[0];  // (32,2048,256)
    const float* pre    = (const float*)d_in[1];  // (32,2048,256)
    const float* r_proj = (const float*)d_in[2];  // (256,256)
    const float* inc    = (const float*)d_in[3];  // (2048,2048)
    float* out = (float*)d_out;                   // [0..31]=loss, [32..]=incidence

    char* ws = (char*)d_ws;
    unsigned short* Wneg   = (unsigned short*)(ws + 0);          //  8 MB
    unsigned short* preT   = (unsigned short*)(ws + 8388608);    // 32 MB
    unsigned short* rprojT = (unsigned short*)(ws + 41943040);   // 128 KB
    float*          crow   = (float*)(ws + 42336256);            // 8 KB
    unsigned short* curbf  = (unsigned short*)(ws + 42344448);   // 16 MB

    prep_all<<<8208, 256, 0, stream>>>(inc, out + 32, Wneg, crow,
                                       pre, preT, r_proj, rprojT,
                                       cur, curbf, out);
    gemm_diff<<<512, 512, 0, stream>>>(Wneg, curbf, preT, rprojT, crow, out);
}

// Round 7
// 242.727 us; speedup vs baseline: 1.0682x; 1.0682x over previous
//
#include <hip/hip_runtime.h>

// ---------------------------------------------------------------------------
// TemporalHyperedge: loss[b] = 0.2 * sum_n ||cur[b]@r_proj - W@pre[b]||_2
//                              + sum_n (max_m W[n,m] + 0.001*||W[n,:]||_2)
// W = incidence_m masked to > 0.01. Output = [loss(32) , incidence_m(2048^2)].
//
// R11 change: gemm_diff rebuilt as a faithful port of the verified 256x256
// 8-phase template (m201, 62% MfmaUtil): 512 thr / 8 waves (2m x 4n),
// mfma_f32_16x16x32_bf16, wave tile 128x64 (acc f32x4[8][4]), LDS
// [2buf][256 rows][64 k] for A and B^T (128 KB), row-spread swizzle
// byte ^= (row&7)<<4 (full 8-slot spread; previous 2-bit swizzles left a
// 4-way/16-bank pattern). Phases = (qa m-half, kh k-half), 16 MFMA each,
// stage units (16KB, 2 GLL16/thread) at the template's exact slots with
// vmcnt(2) at ph4/ph8 only. Six falsified theories (depth, occupancy,
// LDS bytes, HBM bytes, sync domains) left one invariant: LDS-port and
// MFMA serialize (~3400cyc/tile); the template's fine per-phase interleave
// is the only measured fix (m196/m201). prep/epilogue/remap = R9.
// ---------------------------------------------------------------------------

typedef __attribute__((ext_vector_type(8))) short bf16x8;
typedef __attribute__((ext_vector_type(8))) unsigned short ushort8;
typedef __attribute__((ext_vector_type(4))) float f32x4;

__device__ __forceinline__ unsigned short f2bf(float f) {
    union { float f; unsigned u; } x; x.f = f;
    unsigned r = x.u + 0x7fffu + ((x.u >> 16) & 1u);   // RNE
    return (unsigned short)(r >> 16);
}

#define GLL16(g, l)                                                         \
    __builtin_amdgcn_global_load_lds(                                       \
        (const __attribute__((address_space(1))) void*)(g),                 \
        (__attribute__((address_space(3))) void*)(l), 16, 0, 0)

// --------------------------------------------------------------------------
// transpose_64x64: src f32 (R,C) tile (r0,c0) -> dst bf16 (C,R).
// --------------------------------------------------------------------------
__device__ __forceinline__ void transpose_64x64(
    const float* __restrict__ src, unsigned short* __restrict__ dst,
    int R, int C, int r0, int c0, unsigned short* __restrict__ tile) {
    const int t = threadIdx.x;
    const int fr = t >> 4, fc = (t & 15) * 4;
#pragma unroll
    for (int it = 0; it < 4; ++it) {
        int m = fr + it * 16;
        float4 v = *(const float4*)(src + (size_t)(r0 + m) * C + c0 + fc);
        tile[(fc + 0) * 68 + m] = f2bf(v.x);
        tile[(fc + 1) * 68 + m] = f2bf(v.y);
        tile[(fc + 2) * 68 + m] = f2bf(v.z);
        tile[(fc + 3) * 68 + m] = f2bf(v.w);
    }
    __syncthreads();
    const int d = t >> 2, m0 = (t & 3) * 16;
    unsigned short v[16];
#pragma unroll
    for (int j = 0; j < 4; ++j)
        *(ushort4*)(v + j * 4) = *(const ushort4*)(tile + d * 68 + m0 + j * 4);
    unsigned short* dp = dst + (size_t)(c0 + d) * R + r0 + m0;
    ushort8 p0, p1;
#pragma unroll
    for (int j = 0; j < 8; ++j) { p0[j] = v[j]; p1[j] = v[8 + j]; }
    *(ushort8*)(dp) = p0;
    *(ushort8*)(dp + 8) = p1;
}

// --------------------------------------------------------------------------
// prep_all — block sections (unchanged from R9):
//   [0,2048)     : incidence row: copy-out, -masked bf16 W, crow=l1+1e-3*l2
//   [2048,6144)  : pre -> preT bf16 transpose
//   [6144,6160)  : r_proj -> rprojT bf16 transpose
//   [6160,8208)  : cur f32 -> curbf bf16
// --------------------------------------------------------------------------
__global__ __launch_bounds__(256) void prep_all(
    const float* __restrict__ inc, float* __restrict__ out_inc,
    unsigned short* __restrict__ Wneg, float* __restrict__ crow,
    const float* __restrict__ pre, unsigned short* __restrict__ preT,
    const float* __restrict__ r_proj, unsigned short* __restrict__ rprojT,
    const float* __restrict__ cur, unsigned short* __restrict__ curbf,
    float* __restrict__ out_loss) {
    __shared__ unsigned short tile[64 * 68];
    __shared__ float smax[4], ssum[4];
    const int bid = blockIdx.x;
    const int t = threadIdx.x;

    if (bid < 2048) {
        if (bid == 0 && t < 32) out_loss[t] = 0.f;
        const int row = bid;
        const float4* src = (const float4*)(inc + (size_t)row * 2048);
        float4* dst = (float4*)(out_inc + (size_t)row * 2048);
        ushort4* wp = (ushort4*)(Wneg + (size_t)row * 2048);
        float lmax = 0.f, ss = 0.f;
#pragma unroll
        for (int it = 0; it < 2; ++it) {
            int i = it * 256 + t;
            float4 v = src[i];
            dst[i] = v;
            float w0 = v.x > 0.01f ? v.x : 0.f;
            float w1 = v.y > 0.01f ? v.y : 0.f;
            float w2 = v.z > 0.01f ? v.z : 0.f;
            float w3 = v.w > 0.01f ? v.w : 0.f;
            ushort4 p;
            p.x = f2bf(-w0); p.y = f2bf(-w1); p.z = f2bf(-w2); p.w = f2bf(-w3);
            wp[i] = p;
            lmax = fmaxf(lmax, fmaxf(fmaxf(w0, w1), fmaxf(w2, w3)));
            ss += w0 * w0 + w1 * w1 + w2 * w2 + w3 * w3;
        }
#pragma unroll
        for (int off = 32; off; off >>= 1) {
            lmax = fmaxf(lmax, __shfl_down(lmax, off));
            ss += __shfl_down(ss, off);
        }
        int wv = t >> 6, ln = t & 63;
        if (ln == 0) { smax[wv] = lmax; ssum[wv] = ss; }
        __syncthreads();
        if (t == 0) {
            float m = fmaxf(fmaxf(smax[0], smax[1]), fmaxf(smax[2], smax[3]));
            float s = ssum[0] + ssum[1] + ssum[2] + ssum[3];
            crow[row] = m + 0.001f * sqrtf(s);
        }
    } else if (bid < 6144) {
        const int tt = bid - 2048;
        const int b = tt >> 7;
        const int mt = (tt & 127) >> 2;
        const int dt = tt & 3;
        transpose_64x64(pre + (size_t)b * 524288, preT + (size_t)b * 524288,
                        2048, 256, mt * 64, dt * 64, tile);
    } else if (bid < 6160) {
        const int tt = bid - 6144;
        transpose_64x64(r_proj, rprojT, 256, 256, (tt >> 2) * 64, (tt & 3) * 64,
                        tile);
    } else {
        const size_t base = (size_t)(bid - 6160) * 8192;
#pragma unroll
        for (int i = 0; i < 8; ++i) {
            size_t idx = base + (size_t)(i * 256 + t) * 4;
            float4 v = *(const float4*)(cur + idx);
            ushort4 p;
            p.x = f2bf(v.x); p.y = f2bf(v.y); p.z = f2bf(v.z); p.w = f2bf(v.w);
            *(ushort4*)(curbf + idx) = p;
        }
    }
}

// --------------------------------------------------------------------------
// gemm_diff: m201-template port. 256 blocks (XCD remap: panel x batch),
// 512 thr / 8 waves (wm 0..1, wn 0..3), wave tile 128x64, 16x16x32 MFMA,
// K = 2304 = 36 BK=64 tiles (t<32: Wneg/preT; t>=32: curbf/rprojT).
//
// LDS: A[2buf][256 rows][64 k] bf16 (64KB) + B^T same (64KB). Row = 128B.
// Swizzle: byte-in-row ^= (row&7)<<4 (8-slot spread). Staged linearly via
// GLL16 with source-side chunk permute sbyte = ((lane&7)^(lane>>3))*16.
//
// Iteration j computes tiles E=2j (buf0, ph1-4) and O=2j+1 (buf1, ph5-8).
// Phase (qa, kh): read 4 A-frags (+4 B-frags when qa==0), stage one 16KB
// unit, vmcnt(2) at ph4/ph8 only, barrier, setprio1, 16 MFMA, setprio0,
// barrier. Stage slots: ph1: O.Aq1 + O.Bu0; ph2: O.Bu1; ph4: E'.Aq0;
// ph5: E'.Aq1 + E'.Bu0; ph6: E'.Bu1; ph8: O'.Aq0. (Aq = rows {qa*64+[0,64)}
// u {128+qa*64+[0,64)}; Bu = B^T rows u*128+[0,128); all 2 GLL16/thread.)
// WAR: each region freed by the barrier one phase before overwrite.
// RAW: each unit lands >=2 phases + one vmcnt(2) before first read.
//
// Epilogue: ssq row-sums via shfl + atomic, then fused loss reduce (R9).
// --------------------------------------------------------------------------
__global__ __launch_bounds__(512) void gemm_diff(
    const unsigned short* __restrict__ Wneg,    // (2048,2048) bf16 neg+masked
    const unsigned short* __restrict__ curbf,   // (32,2048,256) bf16
    const unsigned short* __restrict__ preT,    // (32,256,2048) bf16
    const unsigned short* __restrict__ rprojT,  // (256,256) bf16
    const float* __restrict__ crow,             // (2048)
    float* __restrict__ out_loss)               // (32)
{
    const int i    = blockIdx.x;                 // 0..255
    const int xcd  = i & 7;
    const int slot = i >> 3;                     // 0..31
    const int n0   = (slot & 7) * 256;           // panel
    const int b    = xcd + ((slot >> 3) << 3);   // batch

    __shared__ unsigned short Ab[2 * 256 * 64];  // 64 KB
    __shared__ unsigned short Bb[2 * 256 * 64];  // 64 KB
    __shared__ float ssq[256];
    __shared__ float red[8];

    const int tid  = threadIdx.x;
    const int w    = tid >> 6;                   // 0..7
    const int lane = tid & 63;
    const int l15  = lane & 15;
    const int kg   = lane >> 4;                  // k-group 0..3
    const int wm   = w >> 2;                     // 0..1 (m-band of 128)
    const int wn   = w & 3;                      // 0..3 (n-band of 64)
    const int srow  = lane >> 3;                 // staging row within 8
    const int sbyte = ((lane & 7) ^ srow) * 16;  // swizzled source chunk
    const int rsw   = (lane & 7) << 4;           // read-side swizzle
    // col-byte (pre-swizzled) for kh = 0 / 1:
    const int csw0 = (kg * 16) ^ rsw;
    const int csw1 = (64 + kg * 16) ^ rsw;

    if (tid < 256) ssq[tid] = 0.f;

    f32x4 acc[8][4] = {};
    bf16x8 bfr[4];

    const unsigned short* curA = curbf + (size_t)b * 2048 * 256 + (size_t)n0 * 256;
    const unsigned short* preB = preT + (size_t)b * 256 * 2048;
    const unsigned short* An   = Wneg + (size_t)n0 * 2048;

    // stage A unit (tile T, quarter qa): rows {qa*64+[0,64)} u {128+qa*64+..}
#define STAGE_A(T, qa)                                                         \
    {                                                                          \
        const int _t = (T);                                                    \
        const char* _ab; size_t _str; int _kk;                                 \
        if (_t < 32) { _ab = (const char*)An;   _str = 4096; _kk = _t * 128; } \
        else { _ab = (const char*)curA; _str = 512; _kk = (_t - 32) * 128; }   \
        _Pragma("unroll") for (int _p = 0; _p < 2; ++_p) {                     \
            const int _rb = (qa) * 64 + _p * 128 + w * 8;                      \
            GLL16(_ab + (size_t)(_rb + srow) * _str + _kk + sbyte,             \
                  (char*)Ab + (_t & 1) * 32768 + _rb * 128);                   \
        }                                                                      \
    }
    // stage B unit (tile T, half u): B^T rows u*128+[0,128)
#define STAGE_B(T, u)                                                          \
    {                                                                          \
        const int _t = (T);                                                    \
        const char* _bb; size_t _str; int _kk;                                 \
        if (_t < 32) { _bb = (const char*)preB;   _str = 4096; _kk = _t * 128; }\
        else { _bb = (const char*)rprojT; _str = 512; _kk = (_t - 32) * 128; } \
        _Pragma("unroll") for (int _p = 0; _p < 2; ++_p) {                     \
            const int _rb = (u) * 128 + _p * 64 + w * 8;                       \
            GLL16(_bb + (size_t)(_rb + srow) * _str + _kk + sbyte,             \
                  (char*)Bb + (_t & 1) * 32768 + _rb * 128);                   \
        }                                                                      \
    }

#define PHASE(BUF, qa, kh, STAGES, VMW)                                        \
    {                                                                          \
        const char* _A = (const char*)Ab + (BUF) * 32768 +                     \
                         (wm * 128 + (qa) * 64) * 128;                         \
        bf16x8 _af[4];                                                         \
        _Pragma("unroll") for (int _m = 0; _m < 4; ++_m)                       \
            _af[_m] = *(const bf16x8*)(_A + (_m * 16 + l15) * 128 +            \
                                       ((kh) ? csw1 : csw0));                  \
        if ((qa) == 0) {                                                       \
            const char* _B = (const char*)Bb + (BUF) * 32768 +                 \
                             (wn * 64) * 128;                                  \
            _Pragma("unroll") for (int _n = 0; _n < 4; ++_n)                   \
                bfr[_n] = *(const bf16x8*)(_B + (_n * 16 + l15) * 128 +        \
                                           ((kh) ? csw1 : csw0));              \
        }                                                                      \
        STAGES                                                                 \
        VMW                                                                    \
        asm volatile("s_barrier" ::: "memory");                                \
        __builtin_amdgcn_s_setprio(1);                                         \
        _Pragma("unroll") for (int _m = 0; _m < 4; ++_m)                       \
        _Pragma("unroll") for (int _n = 0; _n < 4; ++_n)                       \
            acc[(qa) * 4 + _m][_n] = __builtin_amdgcn_mfma_f32_16x16x32_bf16(  \
                _af[_m], bfr[_n], acc[(qa) * 4 + _m][_n], 0, 0, 0);            \
        __builtin_amdgcn_s_setprio(0);                                         \
        asm volatile("s_barrier" ::: "memory");                                \
    }

#define VM2 asm volatile("s_waitcnt vmcnt(2)" ::: "memory");
#define VM0 asm volatile("s_waitcnt vmcnt(0)" ::: "memory");

    // ---- prologue: tile0 complete + tile1.Aq0 (10 loads/thread)
    STAGE_A(0, 0); STAGE_A(0, 1); STAGE_B(0, 0); STAGE_B(0, 1);
    STAGE_A(1, 0);
    VM2                                   // tile0 landed; T1.Aq0 in flight
    asm volatile("s_barrier" ::: "memory");

    for (int j = 0; j < 18; ++j) {
        const int E2 = 2 * j + 2, O2 = 2 * j + 3;
        const bool more = (j < 17);
        // tile E = 2j in buf0
        PHASE(0, 0, 0, { STAGE_A(2 * j + 1, 1); STAGE_B(2 * j + 1, 0); }, {})
        PHASE(0, 1, 0, { STAGE_B(2 * j + 1, 1); }, {})
        PHASE(0, 0, 1, {}, {})
        PHASE(0, 1, 1, { if (more) STAGE_A(E2, 0); },
              { if (more) { VM2 } else { VM0 } })
        // tile O = 2j+1 in buf1
        PHASE(1, 0, 0, { if (more) { STAGE_A(E2, 1); STAGE_B(E2, 0); } }, {})
        PHASE(1, 1, 0, { if (more) STAGE_B(E2, 1); }, {})
        PHASE(1, 0, 1, {}, {})
        PHASE(1, 1, 1, { if (more) STAGE_A(O2, 0); },
              { if (more) { VM2 } else { VM0 } })
    }
    __syncthreads();

    // 16x16x32 C/D layout: col = lane&15, row = (lane>>4)*4 + reg
#pragma unroll
    for (int mf = 0; mf < 8; ++mf)
#pragma unroll
        for (int r = 0; r < 4; ++r) {
            float s = 0.f;
#pragma unroll
            for (int nf = 0; nf < 4; ++nf) {
                float v = acc[mf][nf][r];
                s += v * v;
            }
            s += __shfl_xor(s, 1);
            s += __shfl_xor(s, 2);
            s += __shfl_xor(s, 4);
            s += __shfl_xor(s, 8);
            if (l15 == 0) {
                const int row = wm * 128 + mf * 16 + kg * 4 + r;
                atomicAdd(&ssq[row], s);  // 4-way (wn)
            }
        }
    __syncthreads();

    // epilogue reduce: 0.2*sum_n sqrt(ssq[n]) + sum_{n in panel} crow[n]
    float contrib = 0.f;
    if (tid < 256) contrib = 0.2f * sqrtf(ssq[tid]) + crow[n0 + tid];
#pragma unroll
    for (int off = 32; off; off >>= 1) contrib += __shfl_down(contrib, off);
    if (lane == 0) red[w] = contrib;
    __syncthreads();
    if (tid == 0) {
        float s = 0.f;
#pragma unroll
        for (int k = 0; k < 8; ++k) s += red[k];
        atomicAdd(out_loss + b, s);  // 8 adds per batch
    }
}

// --------------------------------------------------------------------------
extern "C" void kernel_launch(void* const* d_in, const int* in_sizes, int n_in,
                              void* d_out, int out_size, void* d_ws, size_t ws_size,
                              hipStream_t stream) {
    const float* cur    = (const float*)d_in[0];  // (32,2048,256)
    const float* pre    = (const float*)d_in[1];  // (32,2048,256)
    const float* r_proj = (const float*)d_in[2];  // (256,256)
    const float* inc    = (const float*)d_in[3];  // (2048,2048)
    float* out = (float*)d_out;                   // [0..31]=loss, [32..]=incidence

    char* ws = (char*)d_ws;
    unsigned short* Wneg   = (unsigned short*)(ws + 0);          //  8 MB
    unsigned short* preT   = (unsigned short*)(ws + 8388608);    // 32 MB
    unsigned short* rprojT = (unsigned short*)(ws + 41943040);   // 128 KB
    float*          crow   = (float*)(ws + 42336256);            // 8 KB
    unsigned short* curbf  = (unsigned short*)(ws + 42344448);   // 16 MB

    prep_all<<<8208, 256, 0, stream>>>(inc, out + 32, Wneg, crow,
                                       pre, preT, r_proj, rprojT,
                                       cur, curbf, out);
    gemm_diff<<<256, 512, 0, stream>>>(Wneg, curbf, preT, rprojT, crow, out);
}